// Round 1
// baseline (605.192 us; speedup 1.0000x reference)
//
#include <hip/hip_runtime.h>
#include <hip/hip_bf16.h>

typedef __bf16 bf16;
typedef bf16 bf16x8 __attribute__((ext_vector_type(8)));
typedef float f32x4 __attribute__((ext_vector_type(4)));

#define MFMA16(a,b,c) __builtin_amdgcn_mfma_f32_16x16x32_bf16(a,b,c,0,0,0)

// load 8 contiguous fp32 and round to bf16x8 (MFMA fragment)
__device__ inline bf16x8 f32_frag(const float* p) {
  f32x4 a = *(const f32x4*)p;
  f32x4 b = *(const f32x4*)(p + 4);
  bf16x8 r;
  r[0]=(bf16)a[0]; r[1]=(bf16)a[1]; r[2]=(bf16)a[2]; r[3]=(bf16)a[3];
  r[4]=(bf16)b[0]; r[5]=(bf16)b[1]; r[6]=(bf16)b[2]; r[7]=(bf16)b[3];
  return r;
}

// ---------------------------------------------------------------------------
// Fused QKV projection: C = A @ W^T  (A: [8192][512] fp32, W: [512][512] fp32)
// blockIdx.z selects projection (0=Q,1=K,2=V). Output layouts:
//   qh/kh: [h*4+b][tok][dk] bf16   vhT: [h*4+b][dv][tok] bf16 (transposed!)
// ---------------------------------------------------------------------------
__global__ __launch_bounds__(256) void proj_kernel(
    const float* __restrict__ q, const float* __restrict__ k, const float* __restrict__ v,
    const float* __restrict__ Wq, const float* __restrict__ Wk, const float* __restrict__ Wv,
    bf16* __restrict__ qh, bf16* __restrict__ kh, bf16* __restrict__ vhT)
{
  const int p = blockIdx.z;
  const float* A = (p==0) ? q : (p==1) ? k : v;
  const float* W = (p==0) ? Wq : (p==1) ? Wk : Wv;
  const int m0 = blockIdx.x * 64, n0 = blockIdx.y * 64;
  const int l  = threadIdx.x & 63, w = threadIdx.x >> 6;
  const int lr = l & 15, lh = l >> 4;
  const int arow = m0 + w*16 + lr;

  f32x4 zero = {0.f, 0.f, 0.f, 0.f};
  f32x4 acc[4] = {zero, zero, zero, zero};

  for (int kk = 0; kk < 512; kk += 32) {
    bf16x8 af = f32_frag(A + (size_t)arow*512 + kk + lh*8);
#pragma unroll
    for (int t = 0; t < 4; ++t) {
      bf16x8 bf_ = f32_frag(W + (size_t)(n0 + t*16 + lr)*512 + kk + lh*8);
      acc[t] = MFMA16(af, bf_, acc[t]);
    }
  }

#pragma unroll
  for (int t = 0; t < 4; ++t) {
    const int ncol = n0 + t*16 + lr;        // C col = lane&15
    const int h = ncol >> 6, d = ncol & 63;
#pragma unroll
    for (int j = 0; j < 4; ++j) {
      const int m   = m0 + w*16 + lh*4 + j; // C row = (lane>>4)*4 + j
      const int b   = m >> 11, tok = m & 2047;
      const bf16 val = (bf16)acc[t][j];
      if (p == 0)      qh [((size_t)((h<<2)|b)*2048 + tok)*64 + d]   = val;
      else if (p == 1) kh [((size_t)((h<<2)|b)*2048 + tok)*64 + d]   = val;
      else             vhT[((size_t)((h<<2)|b)*64   + d)*2048 + tok] = val;
    }
  }
}

// ---------------------------------------------------------------------------
// Flash-style attention: per block = 1 head-batch x 64 queries (4 waves x 16q)
// ---------------------------------------------------------------------------
__global__ __launch_bounds__(256) void attn_kernel(
    const bf16* __restrict__ qh, const bf16* __restrict__ kh, const bf16* __restrict__ vhT,
    const int* __restrict__ mask, float* __restrict__ attn_out)
{
  const int n  = blockIdx.y;                 // head-batch = h*4+b
  const int w  = threadIdx.x >> 6;
  const int l  = threadIdx.x & 63;
  const int lr = l & 15, lh = l >> 4;
  const int q0 = blockIdx.x*64 + w*16;
  const bf16* qn = qh  + (size_t)n*2048*64;
  const bf16* kn = kh  + (size_t)n*2048*64;
  const bf16* vn = vhT + (size_t)n*64*2048;
  const int*  mn = mask + n*2048;
  const int h = n >> 2, b = n & 3;

  const bf16x8 aq0 = *(const bf16x8*)(qn + (size_t)(q0+lr)*64 + lh*8);
  const bf16x8 aq1 = *(const bf16x8*)(qn + (size_t)(q0+lr)*64 + 32 + lh*8);

  __shared__ bf16 sP[4][16][72];   // +8 pad: 144B row stride -> <=2-way banks

  f32x4 zero = {0.f, 0.f, 0.f, 0.f};
  float m_run[4], s_run[4];
  f32x4 acc[4] = {zero, zero, zero, zero};
#pragma unroll
  for (int j = 0; j < 4; ++j) { m_run[j] = -INFINITY; s_run[j] = 0.f; }

  for (int kt = 0; kt < 2048; kt += 64) {
    // ---- S = Q K^T for 16q x 64k tile
    f32x4 sc[4] = {zero, zero, zero, zero};
#pragma unroll
    for (int t = 0; t < 4; ++t) {
      const bf16* kb = kn + (size_t)(kt + t*16 + lr)*64;
      bf16x8 bk0 = *(const bf16x8*)(kb + lh*8);
      bf16x8 bk1 = *(const bf16x8*)(kb + 32 + lh*8);
      sc[t] = MFMA16(aq0, bk0, sc[t]);
      sc[t] = MFMA16(aq1, bk1, sc[t]);
    }
    // ---- mask + temperature, row max
    float p[4][4], rm[4];
#pragma unroll
    for (int j = 0; j < 4; ++j) rm[j] = -INFINITY;
#pragma unroll
    for (int t = 0; t < 4; ++t) {
      const int mk = mn[kt + t*16 + lr];
#pragma unroll
      for (int j = 0; j < 4; ++j) {
        const float lg = mk ? sc[t][j]*0.125f : -1.25e8f;  // (-1e9)/temp
        p[t][j] = lg;
        rm[j] = fmaxf(rm[j], lg);
      }
    }
#pragma unroll
    for (int off = 1; off < 16; off <<= 1)
#pragma unroll
      for (int j = 0; j < 4; ++j)
        rm[j] = fmaxf(rm[j], __shfl_xor(rm[j], off, 16));
    // ---- online softmax update
    float fac[4];
#pragma unroll
    for (int j = 0; j < 4; ++j) {
      const float mnew = fmaxf(m_run[j], rm[j]);
      fac[j] = __expf(m_run[j] - mnew);   // first iter: exp(-inf)=0
      m_run[j] = mnew;
    }
    float ps[4] = {0.f, 0.f, 0.f, 0.f};
#pragma unroll
    for (int t = 0; t < 4; ++t)
#pragma unroll
      for (int j = 0; j < 4; ++j) {
        p[t][j] = __expf(p[t][j] - m_run[j]);
        ps[j] += p[t][j];
      }
#pragma unroll
    for (int off = 1; off < 16; off <<= 1)
#pragma unroll
      for (int j = 0; j < 4; ++j)
        ps[j] += __shfl_xor(ps[j], off, 16);
#pragma unroll
    for (int j = 0; j < 4; ++j) s_run[j] = s_run[j]*fac[j] + ps[j];
#pragma unroll
    for (int t = 0; t < 4; ++t)
#pragma unroll
      for (int j = 0; j < 4; ++j) acc[t][j] *= fac[j];
    // ---- P -> LDS (C-layout scatter), then A-frag reads
#pragma unroll
    for (int t = 0; t < 4; ++t)
#pragma unroll
      for (int j = 0; j < 4; ++j)
        sP[w][lh*4 + j][t*16 + lr] = (bf16)p[t][j];
    asm volatile("s_waitcnt lgkmcnt(0)" ::: "memory");
#pragma unroll
    for (int s = 0; s < 2; ++s) {
      bf16x8 pa = *(const bf16x8*)(&sP[w][lr][s*32 + lh*8]);
#pragma unroll
      for (int dt = 0; dt < 4; ++dt) {
        bf16x8 bv = *(const bf16x8*)(vn + (size_t)(dt*16 + lr)*2048 + kt + s*32 + lh*8);
        acc[dt] = MFMA16(pa, bv, acc[dt]);
      }
    }
  }
  // ---- normalize + store to attn_out[b][tok][h*64+dv] (fp32)
  float inv[4];
#pragma unroll
  for (int j = 0; j < 4; ++j) inv[j] = 1.f / s_run[j];
#pragma unroll
  for (int dt = 0; dt < 4; ++dt)
#pragma unroll
    for (int j = 0; j < 4; ++j) {
      const int tok = q0 + lh*4 + j;
      const int dv  = dt*16 + lr;
      attn_out[((size_t)(b*2048 + tok))*512 + h*64 + dv] = acc[dt][j]*inv[j];
    }
}

// ---------------------------------------------------------------------------
// LayerNorm of (xa + xb), wave per row. outb (bf16 copy) optional.
// NOTE: no __restrict__ on xa/outf — ln1 runs in-place on d_out.
// ---------------------------------------------------------------------------
__global__ __launch_bounds__(256) void ln_kernel(
    const float* xa, const float* xb,
    const float* __restrict__ g, const float* __restrict__ bb,
    float* outf, bf16* outb)
{
  const int row = blockIdx.x*4 + (threadIdx.x >> 6);
  const int l   = threadIdx.x & 63;
  const float* pa = xa + (size_t)row*512;
  const float* pb = xb + (size_t)row*512;
  f32x4 u0 = *(const f32x4*)(pa + 4*l);
  f32x4 u1 = *(const f32x4*)(pa + 256 + 4*l);
  f32x4 w0 = *(const f32x4*)(pb + 4*l);
  f32x4 w1 = *(const f32x4*)(pb + 256 + 4*l);
  u0 = u0 + w0; u1 = u1 + w1;
  float s = 0.f, sq = 0.f;
#pragma unroll
  for (int e = 0; e < 4; ++e) { s += u0[e] + u1[e]; sq += u0[e]*u0[e] + u1[e]*u1[e]; }
#pragma unroll
  for (int off = 1; off < 64; off <<= 1) {
    s  += __shfl_xor(s,  off, 64);
    sq += __shfl_xor(sq, off, 64);
  }
  const float mean = s * (1.f/512.f);
  const float var  = sq * (1.f/512.f) - mean*mean;
  const float r    = rsqrtf(var + 1e-5f);
  f32x4 g0v = *(const f32x4*)(g + 4*l),  g1v = *(const f32x4*)(g + 256 + 4*l);
  f32x4 b0v = *(const f32x4*)(bb + 4*l), b1v = *(const f32x4*)(bb + 256 + 4*l);
  f32x4 o0, o1;
#pragma unroll
  for (int e = 0; e < 4; ++e) {
    o0[e] = (u0[e] - mean)*r*g0v[e] + b0v[e];
    o1[e] = (u1[e] - mean)*r*g1v[e] + b1v[e];
  }
  *(f32x4*)(outf + (size_t)row*512 + 4*l)       = o0;
  *(f32x4*)(outf + (size_t)row*512 + 256 + 4*l) = o1;
  if (outb) {
#pragma unroll
    for (int e = 0; e < 4; ++e) {
      outb[(size_t)row*512 + 4*l + e]       = (bf16)o0[e];
      outb[(size_t)row*512 + 256 + 4*l + e] = (bf16)o1[e];
    }
  }
}

// ---------------------------------------------------------------------------
// FC: out = A(bf16) @ W^T(fp32->bf16) + bias, fp32 out (into d_out; LN1 follows)
// ---------------------------------------------------------------------------
__global__ __launch_bounds__(256) void fc_kernel(
    const bf16* __restrict__ A, const float* __restrict__ W,
    const float* __restrict__ bias, float* __restrict__ out)
{
  const int m0 = blockIdx.x * 64, n0 = blockIdx.y * 64;
  const int l  = threadIdx.x & 63, w = threadIdx.x >> 6;
  const int lr = l & 15, lh = l >> 4;
  const int arow = m0 + w*16 + lr;

  f32x4 zero = {0.f, 0.f, 0.f, 0.f};
  f32x4 acc[4] = {zero, zero, zero, zero};

  for (int kk = 0; kk < 512; kk += 32) {
    bf16x8 af = *(const bf16x8*)(A + (size_t)arow*512 + kk + lh*8);
#pragma unroll
    for (int t = 0; t < 4; ++t) {
      bf16x8 bf_ = f32_frag(W + (size_t)(n0 + t*16 + lr)*512 + kk + lh*8);
      acc[t] = MFMA16(af, bf_, acc[t]);
    }
  }
#pragma unroll
  for (int t = 0; t < 4; ++t) {
    const int ncol = n0 + t*16 + lr;
    const float bs = bias[ncol];
#pragma unroll
    for (int j = 0; j < 4; ++j) {
      const int m = m0 + w*16 + lh*4 + j;
      out[(size_t)m*512 + ncol] = acc[t][j] + bs;
    }
  }
}

// ---------------------------------------------------------------------------
extern "C" void kernel_launch(void* const* d_in, const int* in_sizes, int n_in,
                              void* d_out, int out_size, void* d_ws, size_t ws_size,
                              hipStream_t stream) {
  const float* q    = (const float*)d_in[0];
  const float* k    = (const float*)d_in[1];
  const float* v    = (const float*)d_in[2];
  const int*   mask = (const int*)  d_in[3];
  const float* Wq   = (const float*)d_in[4];
  const float* Wk   = (const float*)d_in[5];
  const float* Wv   = (const float*)d_in[6];
  const float* fcw  = (const float*)d_in[7];
  const float* fcb  = (const float*)d_in[8];
  const float* g0   = (const float*)d_in[9];
  const float* b0   = (const float*)d_in[10];
  const float* g1   = (const float*)d_in[11];
  const float* b1   = (const float*)d_in[12];

  char* ws = (char*)d_ws;
  bf16*  qh   = (bf16*) (ws);                  //  8 MB  [32][2048][64]
  bf16*  kh   = (bf16*) (ws + (8ull  << 20));  //  8 MB  [32][2048][64]
  bf16*  vhT  = (bf16*) (ws + (16ull << 20));  //  8 MB  [32][64][2048]
  float* attn = (float*)(ws + (24ull << 20));  // 16 MB  [4][2048][512]
  float* x1   = (float*)(ws + (40ull << 20));  // 16 MB
  bf16*  x1b  = (bf16*) (ws + (56ull << 20));  //  8 MB   (total 64 MB)
  float* out  = (float*)d_out;

  proj_kernel<<<dim3(128, 8, 3), 256, 0, stream>>>(q, k, v, Wq, Wk, Wv, qh, kh, vhT);
  attn_kernel<<<dim3(32, 32),    256, 0, stream>>>(qh, kh, vhT, mask, attn);
  ln_kernel  <<<2048,            256, 0, stream>>>(attn, q, g0, b0, x1, x1b);
  fc_kernel  <<<dim3(128, 8),    256, 0, stream>>>(x1b, fcw, fcb, out);
  ln_kernel  <<<2048,            256, 0, stream>>>(out, x1, g1, b1, out, nullptr);
}

// Round 4
// 368.902 us; speedup vs baseline: 1.6405x; 1.6405x over previous
//
#include <hip/hip_runtime.h>
#include <hip/hip_bf16.h>

typedef __bf16 bf16;
typedef bf16 bf16x8 __attribute__((ext_vector_type(8)));
typedef bf16 bf16x4 __attribute__((ext_vector_type(4)));
typedef float f32x4 __attribute__((ext_vector_type(4)));

#define MFMA16(a,b,c) __builtin_amdgcn_mfma_f32_16x16x32_bf16(a,b,c,0,0,0)

// ---------------------------------------------------------------------------
// Bulk fp32 -> bf16 conversion. y selects the array.
// ---------------------------------------------------------------------------
__global__ __launch_bounds__(256) void cvt_kernel(
    const float* __restrict__ q, const float* __restrict__ k_, const float* __restrict__ v,
    const float* __restrict__ Wq, const float* __restrict__ Wk, const float* __restrict__ Wv,
    const float* __restrict__ fcw,
    bf16* __restrict__ qb, bf16* __restrict__ kb, bf16* __restrict__ vb,
    bf16* __restrict__ Wqb, bf16* __restrict__ Wkb, bf16* __restrict__ Wvb,
    bf16* __restrict__ fcwb)
{
  const int y = blockIdx.y;
  const float* src; bf16* dst; int n;
  if      (y==0) { src=q;   dst=qb;   n=4194304; }
  else if (y==1) { src=k_;  dst=kb;   n=4194304; }
  else if (y==2) { src=v;   dst=vb;   n=4194304; }
  else if (y==3) { src=Wq;  dst=Wqb;  n=262144;  }
  else if (y==4) { src=Wk;  dst=Wkb;  n=262144;  }
  else if (y==5) { src=Wv;  dst=Wvb;  n=262144;  }
  else           { src=fcw; dst=fcwb; n=262144;  }
  const int i = (blockIdx.x*256 + threadIdx.x)*4;
  if (i >= n) return;
  f32x4 x = *(const f32x4*)(src + i);
  bf16x4 o;
  o[0]=(bf16)x[0]; o[1]=(bf16)x[1]; o[2]=(bf16)x[2]; o[3]=(bf16)x[3];
  *(bf16x4*)(dst + i) = o;
}

// ---------------------------------------------------------------------------
// QKV projection (bf16 in): 128x64 tile/block, wave = 32 rows x 64 cols.
// qh gets the softmax scale (0.125*log2e) folded in. vhT stored transposed.
// ---------------------------------------------------------------------------
__global__ __launch_bounds__(256) void proj_kernel(
    const bf16* __restrict__ qb, const bf16* __restrict__ kb, const bf16* __restrict__ vb,
    const bf16* __restrict__ Wqb, const bf16* __restrict__ Wkb, const bf16* __restrict__ Wvb,
    bf16* __restrict__ qh, bf16* __restrict__ kh, bf16* __restrict__ vhT)
{
  const int p = blockIdx.z;
  const bf16* A = (p==0)?qb:(p==1)?kb:vb;
  const bf16* W = (p==0)?Wqb:(p==1)?Wkb:Wvb;
  const int m0 = blockIdx.x*128, n0 = blockIdx.y*64;
  const int l  = threadIdx.x & 63, w = threadIdx.x >> 6;
  const int lr = l & 15, lh = l >> 4;
  const int r0 = m0 + w*32 + lr, r1 = r0 + 16;

  f32x4 zero = {0.f,0.f,0.f,0.f};
  f32x4 acc[2][4] = {{zero,zero,zero,zero},{zero,zero,zero,zero}};

  for (int kk = 0; kk < 512; kk += 32) {
    bf16x8 a0 = *(const bf16x8*)(A + (size_t)r0*512 + kk + lh*8);
    bf16x8 a1 = *(const bf16x8*)(A + (size_t)r1*512 + kk + lh*8);
#pragma unroll
    for (int t = 0; t < 4; ++t) {
      bf16x8 wf = *(const bf16x8*)(W + (size_t)(n0 + t*16 + lr)*512 + kk + lh*8);
      acc[0][t] = MFMA16(a0, wf, acc[0][t]);
      acc[1][t] = MFMA16(a1, wf, acc[1][t]);
    }
  }

  const float qscale = 0.18033688011112042f;  // 0.125 * log2(e)
#pragma unroll
  for (int g = 0; g < 2; ++g)
#pragma unroll
    for (int t = 0; t < 4; ++t) {
      const int ncol = n0 + t*16 + lr;
      const int h = ncol >> 6, d = ncol & 63;
#pragma unroll
      for (int j = 0; j < 4; ++j) {
        const int m   = m0 + w*32 + g*16 + lh*4 + j;
        const int b   = m >> 11, tok = m & 2047;
        float val = acc[g][t][j];
        if (p == 0) val *= qscale;
        const bf16 bv = (bf16)val;
        if (p == 0)      qh [((size_t)((h<<2)|b)*2048 + tok)*64 + d]   = bv;
        else if (p == 1) kh [((size_t)((h<<2)|b)*2048 + tok)*64 + d]   = bv;
        else             vhT[((size_t)((h<<2)|b)*64   + d)*2048 + tok] = bv;
      }
    }
}

// ---------------------------------------------------------------------------
// Attention v4 (BISECT): round-3 algebra (smask, exp2-clamped, deferred sum)
// with round-1 memory structure (fresh K/V loads at use, NO register
// prefetch arrays). Block = 1 head-batch x 64 queries (4 waves x 16q).
// ---------------------------------------------------------------------------
__global__ __launch_bounds__(256) void attn_kernel(
    const bf16* __restrict__ qh, const bf16* __restrict__ kh, const bf16* __restrict__ vhT,
    const int* __restrict__ mask, float* __restrict__ attn_out)
{
  const int n  = blockIdx.y;
  const int w  = threadIdx.x >> 6;
  const int l  = threadIdx.x & 63;
  const int lr = l & 15, lh = l >> 4;
  const int q0 = blockIdx.x*64 + w*16;
  const bf16* qn = qh  + (size_t)n*2048*64;
  const bf16* kn = kh  + (size_t)n*2048*64;
  const bf16* vn = vhT + (size_t)n*64*2048;
  const int h = n >> 2, b = n & 3;

  __shared__ float smask[2048];
  __shared__ bf16  sP[4][16][72];   // +8 pad
  {
    const int* mn = mask + n*2048;
    const int i0 = (int)threadIdx.x * 8;
    int4 m0v = *(const int4*)(mn + i0);
    int4 m1v = *(const int4*)(mn + i0 + 4);
    f32x4 f0, f1;
    f0[0]=m0v.x?1.f:0.f; f0[1]=m0v.y?1.f:0.f; f0[2]=m0v.z?1.f:0.f; f0[3]=m0v.w?1.f:0.f;
    f1[0]=m1v.x?1.f:0.f; f1[1]=m1v.y?1.f:0.f; f1[2]=m1v.z?1.f:0.f; f1[3]=m1v.w?1.f:0.f;
    *(f32x4*)(smask + i0)     = f0;
    *(f32x4*)(smask + i0 + 4) = f1;
  }
  __syncthreads();

  const bf16x8 aq0 = *(const bf16x8*)(qn + (size_t)(q0+lr)*64 + lh*8);
  const bf16x8 aq1 = *(const bf16x8*)(qn + (size_t)(q0+lr)*64 + 32 + lh*8);

  f32x4 zero = {0.f,0.f,0.f,0.f};
  f32x4 acc[4] = {zero,zero,zero,zero};
  float ssum[4] = {0.f,0.f,0.f,0.f};

#pragma unroll 1
  for (int kt = 0; kt < 2048; kt += 64) {
    // ---- S = Q K^T (scale pre-folded into qh), fresh K loads
    f32x4 sc[4] = {zero,zero,zero,zero};
#pragma unroll
    for (int t = 0; t < 4; ++t) {
      const bf16* kb_ = kn + (size_t)(kt + t*16 + lr)*64;
      bf16x8 bk0 = *(const bf16x8*)(kb_ + lh*8);
      bf16x8 bk1 = *(const bf16x8*)(kb_ + 32 + lh*8);
      sc[t] = MFMA16(aq0, bk0, sc[t]);
      sc[t] = MFMA16(aq1, bk1, sc[t]);
    }
    // ---- unnormalized masked softmax: p = 2^min(sc,100) * m01, deferred sum
    float p[4][4];
#pragma unroll
    for (int t = 0; t < 4; ++t) {
      const float msk = smask[kt + t*16 + lr];
#pragma unroll
      for (int j = 0; j < 4; ++j) {
        const float e = exp2f(fminf(sc[t][j], 100.f)) * msk;
        p[t][j] = e;
        ssum[j] += e;
      }
    }
    // ---- P -> LDS (C-layout scatter), then A-frag reads; fresh V loads
#pragma unroll
    for (int t = 0; t < 4; ++t)
#pragma unroll
      for (int j = 0; j < 4; ++j)
        sP[w][lh*4 + j][t*16 + lr] = (bf16)p[t][j];
    asm volatile("s_waitcnt lgkmcnt(0)" ::: "memory");
#pragma unroll
    for (int s = 0; s < 2; ++s) {
      bf16x8 pa = *(const bf16x8*)(&sP[w][lr][s*32 + lh*8]);
#pragma unroll
      for (int dt = 0; dt < 4; ++dt) {
        bf16x8 bv = *(const bf16x8*)(vn + (size_t)(dt*16 + lr)*2048 + kt + s*32 + lh*8);
        acc[dt] = MFMA16(pa, bv, acc[dt]);
      }
    }
  }

  // ---- single deferred reduction over the 16 lanes of each lh-group
#pragma unroll
  for (int off = 1; off < 16; off <<= 1)
#pragma unroll
    for (int j = 0; j < 4; ++j)
      ssum[j] += __shfl_xor(ssum[j], off, 16);
  float inv[4];
#pragma unroll
  for (int j = 0; j < 4; ++j) inv[j] = (ssum[j] > 0.f) ? 1.f/ssum[j] : 0.f;
#pragma unroll
  for (int dt = 0; dt < 4; ++dt)
#pragma unroll
    for (int j = 0; j < 4; ++j) {
      const int tok = q0 + lh*4 + j;
      const int dv  = dt*16 + lr;
      attn_out[((size_t)(b*2048 + tok))*512 + h*64 + dv] = acc[dt][j]*inv[j];
    }
}

// ---------------------------------------------------------------------------
// LayerNorm of (xa + xb), wave per row. outb (bf16 copy) optional.
// NOTE: no __restrict__ on xa/outf — ln2 runs in-place on d_out.
// ---------------------------------------------------------------------------
__global__ __launch_bounds__(256) void ln_kernel(
    const float* xa, const float* xb,
    const float* __restrict__ g, const float* __restrict__ bb,
    float* outf, bf16* outb)
{
  const int row = blockIdx.x*4 + (threadIdx.x >> 6);
  const int l   = threadIdx.x & 63;
  const float* pa = xa + (size_t)row*512;
  const float* pb = xb + (size_t)row*512;
  f32x4 u0 = *(const f32x4*)(pa + 4*l);
  f32x4 u1 = *(const f32x4*)(pa + 256 + 4*l);
  f32x4 w0 = *(const f32x4*)(pb + 4*l);
  f32x4 w1 = *(const f32x4*)(pb + 256 + 4*l);
  u0 = u0 + w0; u1 = u1 + w1;
  float s = 0.f, sq = 0.f;
#pragma unroll
  for (int e = 0; e < 4; ++e) { s += u0[e] + u1[e]; sq += u0[e]*u0[e] + u1[e]*u1[e]; }
#pragma unroll
  for (int off = 1; off < 64; off <<= 1) {
    s  += __shfl_xor(s,  off, 64);
    sq += __shfl_xor(sq, off, 64);
  }
  const float mean = s * (1.f/512.f);
  const float var  = fmaxf(sq * (1.f/512.f) - mean*mean, 0.f);
  const float r    = rsqrtf(var + 1e-5f);
  f32x4 g0v = *(const f32x4*)(g + 4*l),  g1v = *(const f32x4*)(g + 256 + 4*l);
  f32x4 b0v = *(const f32x4*)(bb + 4*l), b1v = *(const f32x4*)(bb + 256 + 4*l);
  f32x4 o0, o1;
#pragma unroll
  for (int e = 0; e < 4; ++e) {
    o0[e] = (u0[e] - mean)*r*g0v[e] + b0v[e];
    o1[e] = (u1[e] - mean)*r*g1v[e] + b1v[e];
  }
  *(f32x4*)(outf + (size_t)row*512 + 4*l)       = o0;
  *(f32x4*)(outf + (size_t)row*512 + 256 + 4*l) = o1;
  if (outb) {
    bf16x4 ob0, ob1;
#pragma unroll
    for (int e = 0; e < 4; ++e) { ob0[e]=(bf16)o0[e]; ob1[e]=(bf16)o1[e]; }
    *(bf16x4*)(outb + (size_t)row*512 + 4*l)       = ob0;
    *(bf16x4*)(outb + (size_t)row*512 + 256 + 4*l) = ob1;
  }
}

// ---------------------------------------------------------------------------
// FC: out = A(bf16) @ W^T(bf16) + bias, fp32 out (into d_out; LN2 follows)
// ---------------------------------------------------------------------------
__global__ __launch_bounds__(256) void fc_kernel(
    const bf16* __restrict__ A, const bf16* __restrict__ W,
    const float* __restrict__ bias, float* __restrict__ out)
{
  const int m0 = blockIdx.x*128, n0 = blockIdx.y*64;
  const int l  = threadIdx.x & 63, w = threadIdx.x >> 6;
  const int lr = l & 15, lh = l >> 4;
  const int r0 = m0 + w*32 + lr, r1 = r0 + 16;

  f32x4 zero = {0.f,0.f,0.f,0.f};
  f32x4 acc[2][4] = {{zero,zero,zero,zero},{zero,zero,zero,zero}};

  for (int kk = 0; kk < 512; kk += 32) {
    bf16x8 a0 = *(const bf16x8*)(A + (size_t)r0*512 + kk + lh*8);
    bf16x8 a1 = *(const bf16x8*)(A + (size_t)r1*512 + kk + lh*8);
#pragma unroll
    for (int t = 0; t < 4; ++t) {
      bf16x8 wf = *(const bf16x8*)(W + (size_t)(n0 + t*16 + lr)*512 + kk + lh*8);
      acc[0][t] = MFMA16(a0, wf, acc[0][t]);
      acc[1][t] = MFMA16(a1, wf, acc[1][t]);
    }
  }
#pragma unroll
  for (int g = 0; g < 2; ++g)
#pragma unroll
    for (int t = 0; t < 4; ++t) {
      const int ncol = n0 + t*16 + lr;
      const float bs = bias[ncol];
#pragma unroll
      for (int j = 0; j < 4; ++j) {
        const int m = m0 + w*32 + g*16 + lh*4 + j;
        out[(size_t)m*512 + ncol] = acc[g][t][j] + bs;
      }
    }
}

// ---------------------------------------------------------------------------
extern "C" void kernel_launch(void* const* d_in, const int* in_sizes, int n_in,
                              void* d_out, int out_size, void* d_ws, size_t ws_size,
                              hipStream_t stream) {
  const float* q    = (const float*)d_in[0];
  const float* k    = (const float*)d_in[1];
  const float* v    = (const float*)d_in[2];
  const int*   mask = (const int*)  d_in[3];
  const float* Wq   = (const float*)d_in[4];
  const float* Wk   = (const float*)d_in[5];
  const float* Wv   = (const float*)d_in[6];
  const float* fcw  = (const float*)d_in[7];
  const float* fcb  = (const float*)d_in[8];
  const float* g0   = (const float*)d_in[9];
  const float* b0   = (const float*)d_in[10];
  const float* g1   = (const float*)d_in[11];
  const float* b1   = (const float*)d_in[12];

  char* ws = (char*)d_ws;
  // live [cvt, proj/fc]:
  bf16*  qb   = (bf16*) (ws);                                  //  8 MB [0,8)
  bf16*  kb   = (bf16*) (ws + (8ull  << 20));                  //  8 MB [8,16)
  bf16*  vb   = (bf16*) (ws + (16ull << 20));                  //  8 MB [16,24)
  bf16*  Wqb  = (bf16*) (ws + (24ull << 20));                  // [24,24.5)
  bf16*  Wkb  = (bf16*) (ws + (24ull << 20) + (512ull << 10)); // [24.5,25)
  bf16*  Wvb  = (bf16*) (ws + (25ull << 20));                  // [25,25.5)
  bf16*  fcwb = (bf16*) (ws + (25ull << 20) + (512ull << 10)); // [25.5,26)
  // live [proj, attn]:
  bf16*  qh   = (bf16*) (ws + (26ull << 20));                  //  8 MB [26,34)
  bf16*  kh   = (bf16*) (ws + (34ull << 20));                  //  8 MB [34,42)
  bf16*  vhT  = (bf16*) (ws + (42ull << 20));                  //  8 MB [42,50)
  // aliased (lifetimes disjoint):
  float* attnb= (float*)(ws);                                  // 16 MB over qb+kb (dead)
  float* x1   = (float*)(ws + (26ull << 20));                  // 16 MB over qh+kh (dead)
  bf16*  x1b  = (bf16*) (ws + (50ull << 20));                  //  8 MB [50,58) fresh
  float* out  = (float*)d_out;

  cvt_kernel <<<dim3(4096, 7), 256, 0, stream>>>(q, k, v, Wq, Wk, Wv, fcw,
                                                 qb, kb, vb, Wqb, Wkb, Wvb, fcwb);
  proj_kernel<<<dim3(64, 8, 3), 256, 0, stream>>>(qb, kb, vb, Wqb, Wkb, Wvb, qh, kh, vhT);
  attn_kernel<<<dim3(32, 32),   256, 0, stream>>>(qh, kh, vhT, mask, attnb);
  ln_kernel  <<<2048,           256, 0, stream>>>(attnb, q, g0, b0, x1, x1b);
  fc_kernel  <<<dim3(64, 8),    256, 0, stream>>>(x1b, fcwb, fcb, out);
  ln_kernel  <<<2048,           256, 0, stream>>>(out, x1, g1, b1, out, nullptr);
}

// Round 5
// 232.514 us; speedup vs baseline: 2.6028x; 1.5866x over previous
//
#include <hip/hip_runtime.h>
#include <hip/hip_bf16.h>

typedef __bf16 bf16;
typedef bf16 bf16x8 __attribute__((ext_vector_type(8)));
typedef bf16 bf16x4 __attribute__((ext_vector_type(4)));
typedef float f32x4 __attribute__((ext_vector_type(4)));

#define MFMA16(a,b,c) __builtin_amdgcn_mfma_f32_16x16x32_bf16(a,b,c,0,0,0)

// async global->LDS, 16B per lane; LDS dest = wave-uniform base + lane*16
__device__ inline void gload_lds16(const bf16* g, bf16* l) {
  __builtin_amdgcn_global_load_lds(
      (const __attribute__((address_space(1))) unsigned int*)g,
      (__attribute__((address_space(3))) unsigned int*)l,
      16, 0, 0);
}

// ---------------------------------------------------------------------------
// Bulk fp32 -> bf16 conversion. y selects the array.
// ---------------------------------------------------------------------------
__global__ __launch_bounds__(256) void cvt_kernel(
    const float* __restrict__ q, const float* __restrict__ k_, const float* __restrict__ v,
    const float* __restrict__ Wq, const float* __restrict__ Wk, const float* __restrict__ Wv,
    const float* __restrict__ fcw,
    bf16* __restrict__ qb, bf16* __restrict__ kb, bf16* __restrict__ vb,
    bf16* __restrict__ Wqb, bf16* __restrict__ Wkb, bf16* __restrict__ Wvb,
    bf16* __restrict__ fcwb)
{
  const int y = blockIdx.y;
  const float* src; bf16* dst; int n;
  if      (y==0) { src=q;   dst=qb;   n=4194304; }
  else if (y==1) { src=k_;  dst=kb;   n=4194304; }
  else if (y==2) { src=v;   dst=vb;   n=4194304; }
  else if (y==3) { src=Wq;  dst=Wqb;  n=262144;  }
  else if (y==4) { src=Wk;  dst=Wkb;  n=262144;  }
  else if (y==5) { src=Wv;  dst=Wvb;  n=262144;  }
  else           { src=fcw; dst=fcwb; n=262144;  }
  const int i = (blockIdx.x*256 + threadIdx.x)*4;
  if (i >= n) return;
  f32x4 x = *(const f32x4*)(src + i);
  bf16x4 o;
  o[0]=(bf16)x[0]; o[1]=(bf16)x[1]; o[2]=(bf16)x[2]; o[3]=(bf16)x[3];
  *(bf16x4*)(dst + i) = o;
}

// ---------------------------------------------------------------------------
// QKV projection (bf16 in): 128x64 tile/block, wave = 32 rows x 64 cols.
// qh gets the softmax scale (0.125*log2e) folded in. vhT stored transposed.
// ---------------------------------------------------------------------------
__global__ __launch_bounds__(256) void proj_kernel(
    const bf16* __restrict__ qb, const bf16* __restrict__ kb, const bf16* __restrict__ vb,
    const bf16* __restrict__ Wqb, const bf16* __restrict__ Wkb, const bf16* __restrict__ Wvb,
    bf16* __restrict__ qh, bf16* __restrict__ kh, bf16* __restrict__ vhT)
{
  const int p = blockIdx.z;
  const bf16* A = (p==0)?qb:(p==1)?kb:vb;
  const bf16* W = (p==0)?Wqb:(p==1)?Wkb:Wvb;
  const int m0 = blockIdx.x*128, n0 = blockIdx.y*64;
  const int l  = threadIdx.x & 63, w = threadIdx.x >> 6;
  const int lr = l & 15, lh = l >> 4;
  const int r0 = m0 + w*32 + lr, r1 = r0 + 16;

  f32x4 zero = {0.f,0.f,0.f,0.f};
  f32x4 acc[2][4] = {{zero,zero,zero,zero},{zero,zero,zero,zero}};

  for (int kk = 0; kk < 512; kk += 32) {
    bf16x8 a0 = *(const bf16x8*)(A + (size_t)r0*512 + kk + lh*8);
    bf16x8 a1 = *(const bf16x8*)(A + (size_t)r1*512 + kk + lh*8);
#pragma unroll
    for (int t = 0; t < 4; ++t) {
      bf16x8 wf = *(const bf16x8*)(W + (size_t)(n0 + t*16 + lr)*512 + kk + lh*8);
      acc[0][t] = MFMA16(a0, wf, acc[0][t]);
      acc[1][t] = MFMA16(a1, wf, acc[1][t]);
    }
  }

  const float qscale = 0.18033688011112042f;  // 0.125 * log2(e)
#pragma unroll
  for (int g = 0; g < 2; ++g)
#pragma unroll
    for (int t = 0; t < 4; ++t) {
      const int ncol = n0 + t*16 + lr;
      const int h = ncol >> 6, d = ncol & 63;
#pragma unroll
      for (int j = 0; j < 4; ++j) {
        const int m   = m0 + w*32 + g*16 + lh*4 + j;
        const int b   = m >> 11, tok = m & 2047;
        float val = acc[g][t][j];
        if (p == 0) val *= qscale;
        const bf16 bv = (bf16)val;
        if (p == 0)      qh [((size_t)((h<<2)|b)*2048 + tok)*64 + d]   = bv;
        else if (p == 1) kh [((size_t)((h<<2)|b)*2048 + tok)*64 + d]   = bv;
        else             vhT[((size_t)((h<<2)|b)*64   + d)*2048 + tok] = bv;
      }
    }
}

// ---------------------------------------------------------------------------
// Attention v5: LDS double-buffered K/V tiles via global_load_lds (shared by
// all 4 waves), XOR-swizzled (pre-swizzled source + swizzled reads), one
// __syncthreads per iteration (full-fence, race-free). Softmax: unnormalized
// exp2-clamped + deferred sum (round-4 algebra).
// Block = 1 head-batch x 64 queries (4 waves x 16q).
// ---------------------------------------------------------------------------
__global__ __launch_bounds__(256) void attn_kernel(
    const bf16* __restrict__ qh, const bf16* __restrict__ kh, const bf16* __restrict__ vhT,
    const int* __restrict__ mask, float* __restrict__ attn_out)
{
  const int n  = blockIdx.y;
  const int w  = threadIdx.x >> 6;
  const int l  = threadIdx.x & 63;
  const int lr = l & 15, lh = l >> 4;
  const int q0 = blockIdx.x*64 + w*16;
  const bf16* qn = qh  + (size_t)n*2048*64;
  const bf16* kn = kh  + (size_t)n*2048*64;
  const bf16* vn = vhT + (size_t)n*64*2048;
  const int h = n >> 2, b = n & 3;

  __shared__ float smask[2048];
  __shared__ bf16  sK[2][4096];     // 64x64 tile, lds[r][cb] = glob[r][cb^(r&7)]
  __shared__ bf16  sV[2][4096];     // same swizzle, rows = dv, cols = tok-kt
  __shared__ bf16  sP[4][16][72];   // +8 pad; read pattern conflict-free

  // stage one 64-key tile (K 8KB + V 8KB) cooperatively; 2 calls/wave each
  auto stage = [&](bf16* dK, bf16* dV, int kt_) {
#pragma unroll
    for (int c = 0; c < 2; ++c) {
      const int i   = (w*2 + c)*64 + l;     // 16B-chunk index in [0,512)
      const int r   = i >> 3;
      const int cbs = (i & 7) ^ (r & 7);    // pre-swizzled source col-block
      gload_lds16(kn + (size_t)(kt_ + r)*64   + cbs*8, dK + (w*2+c)*512);
      gload_lds16(vn + (size_t)r*2048 + kt_   + cbs*8, dV + (w*2+c)*512);
    }
  };

  {
    const int* mn = mask + n*2048;
    const int i0 = (int)threadIdx.x * 8;
    int4 m0v = *(const int4*)(mn + i0);
    int4 m1v = *(const int4*)(mn + i0 + 4);
    f32x4 f0, f1;
    f0[0]=m0v.x?1.f:0.f; f0[1]=m0v.y?1.f:0.f; f0[2]=m0v.z?1.f:0.f; f0[3]=m0v.w?1.f:0.f;
    f1[0]=m1v.x?1.f:0.f; f1[1]=m1v.y?1.f:0.f; f1[2]=m1v.z?1.f:0.f; f1[3]=m1v.w?1.f:0.f;
    *(f32x4*)(smask + i0)     = f0;
    *(f32x4*)(smask + i0 + 4) = f1;
  }
  stage(sK[0], sV[0], 0);
  __syncthreads();                  // drains stage + smask visible

  const bf16x8 aq0 = *(const bf16x8*)(qn + (size_t)(q0+lr)*64 + lh*8);
  const bf16x8 aq1 = *(const bf16x8*)(qn + (size_t)(q0+lr)*64 + 32 + lh*8);

  f32x4 zero = {0.f,0.f,0.f,0.f};
  f32x4 acc[4] = {zero,zero,zero,zero};
  float ssum[4] = {0.f,0.f,0.f,0.f};

  int cur = 0;
#pragma unroll 1
  for (int kt = 0; kt < 2048; kt += 64) {
    const int ktn = kt + 64;
    if (ktn < 2048) stage(sK[cur^1], sV[cur^1], ktn);   // overlaps compute

    const bf16* sKc = sK[cur];
    const bf16* sVc = sV[cur];
    // swizzled fragment read: glob[r][cb*8..+8] at lds r*64 + (cb^(r&7))*8
    auto ldsfrag = [&](const bf16* base, int r, int cb) -> bf16x8 {
      return *(const bf16x8*)(base + r*64 + (((cb ^ (r & 7)) << 3)));
    };

    // ---- S = Q K^T (scale pre-folded into qh)
    f32x4 sc[4] = {zero,zero,zero,zero};
#pragma unroll
    for (int t = 0; t < 4; ++t) {
      bf16x8 bk0 = ldsfrag(sKc, t*16 + lr, lh);
      bf16x8 bk1 = ldsfrag(sKc, t*16 + lr, lh + 4);
      sc[t] = MFMA16(aq0, bk0, sc[t]);
      sc[t] = MFMA16(aq1, bk1, sc[t]);
    }
    // ---- unnormalized masked softmax: p = 2^min(sc,100) * m01, deferred sum
    float p[4][4];
#pragma unroll
    for (int t = 0; t < 4; ++t) {
      const float msk = smask[kt + t*16 + lr];
#pragma unroll
      for (int j = 0; j < 4; ++j) {
        const float e = exp2f(fminf(sc[t][j], 100.f)) * msk;
        p[t][j] = e;
        ssum[j] += e;
      }
    }
    // ---- P -> LDS (C-layout scatter), then A-frag reads; V from LDS
#pragma unroll
    for (int t = 0; t < 4; ++t)
#pragma unroll
      for (int j = 0; j < 4; ++j)
        sP[w][lh*4 + j][t*16 + lr] = (bf16)p[t][j];
    asm volatile("s_waitcnt lgkmcnt(0)" ::: "memory");
    __builtin_amdgcn_sched_barrier(0);   // rule #18
#pragma unroll
    for (int s = 0; s < 2; ++s) {
      bf16x8 pa = *(const bf16x8*)(&sP[w][lr][s*32 + lh*8]);
#pragma unroll
      for (int dt = 0; dt < 4; ++dt) {
        bf16x8 bv = ldsfrag(sVc, dt*16 + lr, s*4 + lh);
        acc[dt] = MFMA16(pa, bv, acc[dt]);
      }
    }
    __syncthreads();                 // tile consumed by all; next stage safe
    cur ^= 1;
  }

  // ---- single deferred reduction over the 16 lanes of each lh-group
#pragma unroll
  for (int off = 1; off < 16; off <<= 1)
#pragma unroll
    for (int j = 0; j < 4; ++j)
      ssum[j] += __shfl_xor(ssum[j], off, 16);
  float inv[4];
#pragma unroll
  for (int j = 0; j < 4; ++j) inv[j] = (ssum[j] > 0.f) ? 1.f/ssum[j] : 0.f;
#pragma unroll
  for (int dt = 0; dt < 4; ++dt)
#pragma unroll
    for (int j = 0; j < 4; ++j) {
      const int tok = q0 + lh*4 + j;
      const int dv  = dt*16 + lr;
      attn_out[((size_t)(b*2048 + tok))*512 + h*64 + dv] = acc[dt][j]*inv[j];
    }
}

// ---------------------------------------------------------------------------
// LayerNorm of (xa + xb), wave per row. outb (bf16 copy) optional.
// NOTE: no __restrict__ on xa/outf — ln2 runs in-place on d_out.
// ---------------------------------------------------------------------------
__global__ __launch_bounds__(256) void ln_kernel(
    const float* xa, const float* xb,
    const float* __restrict__ g, const float* __restrict__ bb,
    float* outf, bf16* outb)
{
  const int row = blockIdx.x*4 + (threadIdx.x >> 6);
  const int l   = threadIdx.x & 63;
  const float* pa = xa + (size_t)row*512;
  const float* pb = xb + (size_t)row*512;
  f32x4 u0 = *(const f32x4*)(pa + 4*l);
  f32x4 u1 = *(const f32x4*)(pa + 256 + 4*l);
  f32x4 w0 = *(const f32x4*)(pb + 4*l);
  f32x4 w1 = *(const f32x4*)(pb + 256 + 4*l);
  u0 = u0 + w0; u1 = u1 + w1;
  float s = 0.f, sq = 0.f;
#pragma unroll
  for (int e = 0; e < 4; ++e) { s += u0[e] + u1[e]; sq += u0[e]*u0[e] + u1[e]*u1[e]; }
#pragma unroll
  for (int off = 1; off < 64; off <<= 1) {
    s  += __shfl_xor(s,  off, 64);
    sq += __shfl_xor(sq, off, 64);
  }
  const float mean = s * (1.f/512.f);
  const float var  = fmaxf(sq * (1.f/512.f) - mean*mean, 0.f);
  const float r    = rsqrtf(var + 1e-5f);
  f32x4 g0v = *(const f32x4*)(g + 4*l),  g1v = *(const f32x4*)(g + 256 + 4*l);
  f32x4 b0v = *(const f32x4*)(bb + 4*l), b1v = *(const f32x4*)(bb + 256 + 4*l);
  f32x4 o0, o1;
#pragma unroll
  for (int e = 0; e < 4; ++e) {
    o0[e] = (u0[e] - mean)*r*g0v[e] + b0v[e];
    o1[e] = (u1[e] - mean)*r*g1v[e] + b1v[e];
  }
  *(f32x4*)(outf + (size_t)row*512 + 4*l)       = o0;
  *(f32x4*)(outf + (size_t)row*512 + 256 + 4*l) = o1;
  if (outb) {
    bf16x4 ob0, ob1;
#pragma unroll
    for (int e = 0; e < 4; ++e) { ob0[e]=(bf16)o0[e]; ob1[e]=(bf16)o1[e]; }
    *(bf16x4*)(outb + (size_t)row*512 + 4*l)       = ob0;
    *(bf16x4*)(outb + (size_t)row*512 + 256 + 4*l) = ob1;
  }
}

// ---------------------------------------------------------------------------
// FC: out = A(bf16) @ W^T(bf16) + bias, fp32 out (into d_out; LN2 follows)
// ---------------------------------------------------------------------------
__global__ __launch_bounds__(256) void fc_kernel(
    const bf16* __restrict__ A, const bf16* __restrict__ W,
    const float* __restrict__ bias, float* __restrict__ out)
{
  const int m0 = blockIdx.x*128, n0 = blockIdx.y*64;
  const int l  = threadIdx.x & 63, w = threadIdx.x >> 6;
  const int lr = l & 15, lh = l >> 4;
  const int r0 = m0 + w*32 + lr, r1 = r0 + 16;

  f32x4 zero = {0.f,0.f,0.f,0.f};
  f32x4 acc[2][4] = {{zero,zero,zero,zero},{zero,zero,zero,zero}};

  for (int kk = 0; kk < 512; kk += 32) {
    bf16x8 a0 = *(const bf16x8*)(A + (size_t)r0*512 + kk + lh*8);
    bf16x8 a1 = *(const bf16x8*)(A + (size_t)r1*512 + kk + lh*8);
#pragma unroll
    for (int t = 0; t < 4; ++t) {
      bf16x8 wf = *(const bf16x8*)(W + (size_t)(n0 + t*16 + lr)*512 + kk + lh*8);
      acc[0][t] = MFMA16(a0, wf, acc[0][t]);
      acc[1][t] = MFMA16(a1, wf, acc[1][t]);
    }
  }
#pragma unroll
  for (int g = 0; g < 2; ++g)
#pragma unroll
    for (int t = 0; t < 4; ++t) {
      const int ncol = n0 + t*16 + lr;
      const float bs = bias[ncol];
#pragma unroll
      for (int j = 0; j < 4; ++j) {
        const int m = m0 + w*32 + g*16 + lh*4 + j;
        out[(size_t)m*512 + ncol] = acc[g][t][j] + bs;
      }
    }
}

// ---------------------------------------------------------------------------
extern "C" void kernel_launch(void* const* d_in, const int* in_sizes, int n_in,
                              void* d_out, int out_size, void* d_ws, size_t ws_size,
                              hipStream_t stream) {
  const float* q    = (const float*)d_in[0];
  const float* k    = (const float*)d_in[1];
  const float* v    = (const float*)d_in[2];
  const int*   mask = (const int*)  d_in[3];
  const float* Wq   = (const float*)d_in[4];
  const float* Wk   = (const float*)d_in[5];
  const float* Wv   = (const float*)d_in[6];
  const float* fcw  = (const float*)d_in[7];
  const float* fcb  = (const float*)d_in[8];
  const float* g0   = (const float*)d_in[9];
  const float* b0   = (const float*)d_in[10];
  const float* g1   = (const float*)d_in[11];
  const float* b1   = (const float*)d_in[12];

  char* ws = (char*)d_ws;
  // live [cvt, proj/fc]:
  bf16*  qb   = (bf16*) (ws);                                  //  8 MB [0,8)
  bf16*  kb   = (bf16*) (ws + (8ull  << 20));                  //  8 MB [8,16)
  bf16*  vb   = (bf16*) (ws + (16ull << 20));                  //  8 MB [16,24)
  bf16*  Wqb  = (bf16*) (ws + (24ull << 20));                  // [24,24.5)
  bf16*  Wkb  = (bf16*) (ws + (24ull << 20) + (512ull << 10)); // [24.5,25)
  bf16*  Wvb  = (bf16*) (ws + (25ull << 20));                  // [25,25.5)
  bf16*  fcwb = (bf16*) (ws + (25ull << 20) + (512ull << 10)); // [25.5,26)
  // live [proj, attn]:
  bf16*  qh   = (bf16*) (ws + (26ull << 20));                  //  8 MB [26,34)
  bf16*  kh   = (bf16*) (ws + (34ull << 20));                  //  8 MB [34,42)
  bf16*  vhT  = (bf16*) (ws + (42ull << 20));                  //  8 MB [42,50)
  // aliased (lifetimes disjoint):
  float* attnb= (float*)(ws);                                  // 16 MB over qb+kb (dead)
  float* x1   = (float*)(ws + (26ull << 20));                  // 16 MB over qh+kh (dead)
  bf16*  x1b  = (bf16*) (ws + (50ull << 20));                  //  8 MB [50,58) fresh
  float* out  = (float*)d_out;

  cvt_kernel <<<dim3(4096, 7), 256, 0, stream>>>(q, k, v, Wq, Wk, Wv, fcw,
                                                 qb, kb, vb, Wqb, Wkb, Wvb, fcwb);
  proj_kernel<<<dim3(64, 8, 3), 256, 0, stream>>>(qb, kb, vb, Wqb, Wkb, Wvb, qh, kh, vhT);
  attn_kernel<<<dim3(32, 32),   256, 0, stream>>>(qh, kh, vhT, mask, attnb);
  ln_kernel  <<<2048,           256, 0, stream>>>(attnb, q, g0, b0, x1, x1b);
  fc_kernel  <<<dim3(64, 8),    256, 0, stream>>>(x1b, fcwb, fcb, out);
  ln_kernel  <<<2048,           256, 0, stream>>>(out, x1, g1, b1, out, nullptr);
}

// Round 6
// 228.404 us; speedup vs baseline: 2.6497x; 1.0180x over previous
//
#include <hip/hip_runtime.h>
#include <hip/hip_bf16.h>

typedef __bf16 bf16;
typedef bf16 bf16x8 __attribute__((ext_vector_type(8)));
typedef bf16 bf16x4 __attribute__((ext_vector_type(4)));
typedef float f32x4 __attribute__((ext_vector_type(4)));

#define MFMA16(a,b,c) __builtin_amdgcn_mfma_f32_16x16x32_bf16(a,b,c,0,0,0)

// async global->LDS, 16B per lane; LDS dest = wave-uniform base + lane*16
__device__ inline void gload_lds16(const bf16* g, bf16* l) {
  __builtin_amdgcn_global_load_lds(
      (const __attribute__((address_space(1))) unsigned int*)g,
      (__attribute__((address_space(3))) unsigned int*)l,
      16, 0, 0);
}

// load 8 contiguous fp32 and round to bf16x8 (MFMA fragment)
__device__ inline bf16x8 f32_frag(const float* p) {
  f32x4 a = *(const f32x4*)p;
  f32x4 b = *(const f32x4*)(p + 4);
  bf16x8 r;
  r[0]=(bf16)a[0]; r[1]=(bf16)a[1]; r[2]=(bf16)a[2]; r[3]=(bf16)a[3];
  r[4]=(bf16)b[0]; r[5]=(bf16)b[1]; r[6]=(bf16)b[2]; r[7]=(bf16)b[3];
  return r;
}

// ---------------------------------------------------------------------------
// fp32 -> bf16 conversion for the four weight matrices only (262144 elems ea).
// ---------------------------------------------------------------------------
__global__ __launch_bounds__(256) void cvt_kernel(
    const float* __restrict__ Wq, const float* __restrict__ Wk,
    const float* __restrict__ Wv, const float* __restrict__ fcw,
    bf16* __restrict__ Wqb, bf16* __restrict__ Wkb,
    bf16* __restrict__ Wvb, bf16* __restrict__ fcwb)
{
  const int y = blockIdx.y;
  const float* src = (y==0)?Wq:(y==1)?Wk:(y==2)?Wv:fcw;
  bf16* dst = (y==0)?Wqb:(y==1)?Wkb:(y==2)?Wvb:fcwb;
  const int i = (blockIdx.x*256 + threadIdx.x)*4;
  f32x4 x = *(const f32x4*)(src + i);
  bf16x4 o;
  o[0]=(bf16)x[0]; o[1]=(bf16)x[1]; o[2]=(bf16)x[2]; o[3]=(bf16)x[3];
  *(bf16x4*)(dst + i) = o;
}

// ---------------------------------------------------------------------------
// QKV projection: A fp32 (in-register cvt, single-use), W bf16 (pre-cvt).
// 128x64 tile/block, wave = 32 rows x 64 cols.
// qh gets the softmax scale (0.125*log2e) folded in. vhT stored transposed.
// ---------------------------------------------------------------------------
__global__ __launch_bounds__(256) void proj_kernel(
    const float* __restrict__ q, const float* __restrict__ k_, const float* __restrict__ v,
    const bf16* __restrict__ Wqb, const bf16* __restrict__ Wkb, const bf16* __restrict__ Wvb,
    bf16* __restrict__ qh, bf16* __restrict__ kh, bf16* __restrict__ vhT)
{
  const int p = blockIdx.z;
  const float* A = (p==0)?q:(p==1)?k_:v;
  const bf16*  W = (p==0)?Wqb:(p==1)?Wkb:Wvb;
  const int m0 = blockIdx.x*128, n0 = blockIdx.y*64;
  const int l  = threadIdx.x & 63, w = threadIdx.x >> 6;
  const int lr = l & 15, lh = l >> 4;
  const int r0 = m0 + w*32 + lr, r1 = r0 + 16;

  f32x4 zero = {0.f,0.f,0.f,0.f};
  f32x4 acc[2][4] = {{zero,zero,zero,zero},{zero,zero,zero,zero}};

  for (int kk = 0; kk < 512; kk += 32) {
    bf16x8 a0 = f32_frag(A + (size_t)r0*512 + kk + lh*8);
    bf16x8 a1 = f32_frag(A + (size_t)r1*512 + kk + lh*8);
#pragma unroll
    for (int t = 0; t < 4; ++t) {
      bf16x8 wf = *(const bf16x8*)(W + (size_t)(n0 + t*16 + lr)*512 + kk + lh*8);
      acc[0][t] = MFMA16(a0, wf, acc[0][t]);
      acc[1][t] = MFMA16(a1, wf, acc[1][t]);
    }
  }

  const float qscale = 0.18033688011112042f;  // 0.125 * log2(e)
#pragma unroll
  for (int g = 0; g < 2; ++g)
#pragma unroll
    for (int t = 0; t < 4; ++t) {
      const int ncol = n0 + t*16 + lr;
      const int h = ncol >> 6, d = ncol & 63;
#pragma unroll
      for (int j = 0; j < 4; ++j) {
        const int m   = m0 + w*32 + g*16 + lh*4 + j;
        const int b   = m >> 11, tok = m & 2047;
        float val = acc[g][t][j];
        if (p == 0) val *= qscale;
        const bf16 bv = (bf16)val;
        if (p == 0)      qh [((size_t)((h<<2)|b)*2048 + tok)*64 + d]   = bv;
        else if (p == 1) kh [((size_t)((h<<2)|b)*2048 + tok)*64 + d]   = bv;
        else             vhT[((size_t)((h<<2)|b)*64   + d)*2048 + tok] = bv;
      }
    }
}

// ---------------------------------------------------------------------------
// Attention v6: 32 queries/wave (128/block). LDS double-buffered K/V via
// global_load_lds + XOR swizzle; K/V fragments register-reused across both
// 16-q groups; sP two-pass (stays 9KB -> 49KB LDS -> 3 blocks/CU).
// Unnormalized exp2-clamped softmax, deferred sum.
// ---------------------------------------------------------------------------
__global__ __launch_bounds__(256, 3) void attn_kernel(
    const bf16* __restrict__ qh, const bf16* __restrict__ kh, const bf16* __restrict__ vhT,
    const int* __restrict__ mask, float* __restrict__ attn_out)
{
  const int n  = blockIdx.y;
  const int w  = threadIdx.x >> 6;
  const int l  = threadIdx.x & 63;
  const int lr = l & 15, lh = l >> 4;
  const int q0 = blockIdx.x*128 + w*32;
  const bf16* qn = qh  + (size_t)n*2048*64;
  const bf16* kn = kh  + (size_t)n*2048*64;
  const bf16* vn = vhT + (size_t)n*64*2048;
  const int h = n >> 2, b = n & 3;

  __shared__ float smask[2048];
  __shared__ bf16  sK[2][4096];     // 64x64 tile, lds[r][cb] = glob[r][cb^(r&7)]
  __shared__ bf16  sV[2][4096];     // same swizzle, rows = dv, cols = tok-kt
  __shared__ bf16  sP[4][16][72];   // +8 pad; per-group staging

  auto stage = [&](bf16* dK, bf16* dV, int kt_) {
#pragma unroll
    for (int c = 0; c < 2; ++c) {
      const int i   = (w*2 + c)*64 + l;     // 16B-chunk index in [0,512)
      const int r   = i >> 3;
      const int cbs = (i & 7) ^ (r & 7);    // pre-swizzled source col-block
      gload_lds16(kn + (size_t)(kt_ + r)*64   + cbs*8, dK + (w*2+c)*512);
      gload_lds16(vn + (size_t)r*2048 + kt_   + cbs*8, dV + (w*2+c)*512);
    }
  };

  {
    const int* mn = mask + n*2048;
    const int i0 = (int)threadIdx.x * 8;
    int4 m0v = *(const int4*)(mn + i0);
    int4 m1v = *(const int4*)(mn + i0 + 4);
    f32x4 f0, f1;
    f0[0]=m0v.x?1.f:0.f; f0[1]=m0v.y?1.f:0.f; f0[2]=m0v.z?1.f:0.f; f0[3]=m0v.w?1.f:0.f;
    f1[0]=m1v.x?1.f:0.f; f1[1]=m1v.y?1.f:0.f; f1[2]=m1v.z?1.f:0.f; f1[3]=m1v.w?1.f:0.f;
    *(f32x4*)(smask + i0)     = f0;
    *(f32x4*)(smask + i0 + 4) = f1;
  }
  stage(sK[0], sV[0], 0);
  __syncthreads();

  bf16x8 aq[2][2];
#pragma unroll
  for (int g = 0; g < 2; ++g) {
    aq[g][0] = *(const bf16x8*)(qn + (size_t)(q0+g*16+lr)*64 + lh*8);
    aq[g][1] = *(const bf16x8*)(qn + (size_t)(q0+g*16+lr)*64 + 32 + lh*8);
  }

  f32x4 zero = {0.f,0.f,0.f,0.f};
  f32x4 acc[2][4] = {{zero,zero,zero,zero},{zero,zero,zero,zero}};
  float ssum[2][4] = {{0.f,0.f,0.f,0.f},{0.f,0.f,0.f,0.f}};

  int cur = 0;
#pragma unroll 1
  for (int kt = 0; kt < 2048; kt += 64) {
    const int ktn = kt + 64;
    if (ktn < 2048) stage(sK[cur^1], sV[cur^1], ktn);

    const bf16* sKc = sK[cur];
    const bf16* sVc = sV[cur];
    auto ldsfrag = [&](const bf16* base, int r, int cb) -> bf16x8 {
      return *(const bf16x8*)(base + r*64 + (((cb ^ (r & 7)) << 3)));
    };

    // ---- S = Q K^T : K frags loaded once, reused by both q-groups
    f32x4 sc[2][4] = {{zero,zero,zero,zero},{zero,zero,zero,zero}};
#pragma unroll
    for (int t = 0; t < 4; ++t) {
      bf16x8 bk0 = ldsfrag(sKc, t*16 + lr, lh);
      bf16x8 bk1 = ldsfrag(sKc, t*16 + lr, lh + 4);
      sc[0][t] = MFMA16(aq[0][0], bk0, sc[0][t]);
      sc[0][t] = MFMA16(aq[0][1], bk1, sc[0][t]);
      sc[1][t] = MFMA16(aq[1][0], bk0, sc[1][t]);
      sc[1][t] = MFMA16(aq[1][1], bk1, sc[1][t]);
    }
    // ---- unnormalized masked softmax (in place), deferred sum
#pragma unroll
    for (int t = 0; t < 4; ++t) {
      const float msk = smask[kt + t*16 + lr];
#pragma unroll
      for (int g = 0; g < 2; ++g)
#pragma unroll
        for (int j = 0; j < 4; ++j) {
          const float e = exp2f(fminf(sc[g][t][j], 100.f)) * msk;
          sc[g][t][j] = e;
          ssum[g][j] += e;
        }
    }
    // ---- V frags loaded once, reused by both q-groups
    bf16x8 vf0[4], vf1[4];
#pragma unroll
    for (int dt = 0; dt < 4; ++dt) {
      vf0[dt] = ldsfrag(sVc, dt*16 + lr, lh);
      vf1[dt] = ldsfrag(sVc, dt*16 + lr, lh + 4);
    }
    // ---- per-group: P -> sP -> A-frags -> PV
#pragma unroll
    for (int g = 0; g < 2; ++g) {
#pragma unroll
      for (int t = 0; t < 4; ++t)
#pragma unroll
        for (int j = 0; j < 4; ++j)
          sP[w][lh*4 + j][t*16 + lr] = (bf16)sc[g][t][j];
      asm volatile("s_waitcnt lgkmcnt(0)" ::: "memory");
      __builtin_amdgcn_sched_barrier(0);   // rule #18
      bf16x8 pa0 = *(const bf16x8*)(&sP[w][lr][lh*8]);
      bf16x8 pa1 = *(const bf16x8*)(&sP[w][lr][32 + lh*8]);
#pragma unroll
      for (int dt = 0; dt < 4; ++dt) {
        acc[g][dt] = MFMA16(pa0, vf0[dt], acc[g][dt]);
        acc[g][dt] = MFMA16(pa1, vf1[dt], acc[g][dt]);
      }
    }
    __syncthreads();
    cur ^= 1;
  }

  // ---- deferred reduction + store
#pragma unroll
  for (int off = 1; off < 16; off <<= 1)
#pragma unroll
    for (int g = 0; g < 2; ++g)
#pragma unroll
      for (int j = 0; j < 4; ++j)
        ssum[g][j] += __shfl_xor(ssum[g][j], off, 16);
#pragma unroll
  for (int g = 0; g < 2; ++g) {
    float inv[4];
#pragma unroll
    for (int j = 0; j < 4; ++j) inv[j] = (ssum[g][j] > 0.f) ? 1.f/ssum[g][j] : 0.f;
#pragma unroll
    for (int dt = 0; dt < 4; ++dt)
#pragma unroll
      for (int j = 0; j < 4; ++j) {
        const int tok = q0 + g*16 + lh*4 + j;
        const int dv  = dt*16 + lr;
        attn_out[((size_t)(b*2048 + tok))*512 + h*64 + dv] = acc[g][dt][j]*inv[j];
      }
  }
}

// ---------------------------------------------------------------------------
// LayerNorm of (xa + xb), wave per row. outb (bf16 copy) optional.
// NOTE: no __restrict__ on xa/outf — ln2 runs in-place on d_out.
// ---------------------------------------------------------------------------
__global__ __launch_bounds__(256) void ln_kernel(
    const float* xa, const float* xb,
    const float* __restrict__ g, const float* __restrict__ bb,
    float* outf, bf16* outb)
{
  const int row = blockIdx.x*4 + (threadIdx.x >> 6);
  const int l   = threadIdx.x & 63;
  const float* pa = xa + (size_t)row*512;
  const float* pb = xb + (size_t)row*512;
  f32x4 u0 = *(const f32x4*)(pa + 4*l);
  f32x4 u1 = *(const f32x4*)(pa + 256 + 4*l);
  f32x4 w0 = *(const f32x4*)(pb + 4*l);
  f32x4 w1 = *(const f32x4*)(pb + 256 + 4*l);
  u0 = u0 + w0; u1 = u1 + w1;
  float s = 0.f, sq = 0.f;
#pragma unroll
  for (int e = 0; e < 4; ++e) { s += u0[e] + u1[e]; sq += u0[e]*u0[e] + u1[e]*u1[e]; }
#pragma unroll
  for (int off = 1; off < 64; off <<= 1) {
    s  += __shfl_xor(s,  off, 64);
    sq += __shfl_xor(sq, off, 64);
  }
  const float mean = s * (1.f/512.f);
  const float var  = fmaxf(sq * (1.f/512.f) - mean*mean, 0.f);
  const float r    = rsqrtf(var + 1e-5f);
  f32x4 g0v = *(const f32x4*)(g + 4*l),  g1v = *(const f32x4*)(g + 256 + 4*l);
  f32x4 b0v = *(const f32x4*)(bb + 4*l), b1v = *(const f32x4*)(bb + 256 + 4*l);
  f32x4 o0, o1;
#pragma unroll
  for (int e = 0; e < 4; ++e) {
    o0[e] = (u0[e] - mean)*r*g0v[e] + b0v[e];
    o1[e] = (u1[e] - mean)*r*g1v[e] + b1v[e];
  }
  *(f32x4*)(outf + (size_t)row*512 + 4*l)       = o0;
  *(f32x4*)(outf + (size_t)row*512 + 256 + 4*l) = o1;
  if (outb) {
    bf16x4 ob0, ob1;
#pragma unroll
    for (int e = 0; e < 4; ++e) { ob0[e]=(bf16)o0[e]; ob1[e]=(bf16)o1[e]; }
    *(bf16x4*)(outb + (size_t)row*512 + 4*l)       = ob0;
    *(bf16x4*)(outb + (size_t)row*512 + 256 + 4*l) = ob1;
  }
}

// ---------------------------------------------------------------------------
// FC: out = A(bf16) @ W^T(bf16) + bias, fp32 out (into d_out; LN2 follows)
// ---------------------------------------------------------------------------
__global__ __launch_bounds__(256) void fc_kernel(
    const bf16* __restrict__ A, const bf16* __restrict__ W,
    const float* __restrict__ bias, float* __restrict__ out)
{
  const int m0 = blockIdx.x*128, n0 = blockIdx.y*64;
  const int l  = threadIdx.x & 63, w = threadIdx.x >> 6;
  const int lr = l & 15, lh = l >> 4;
  const int r0 = m0 + w*32 + lr, r1 = r0 + 16;

  f32x4 zero = {0.f,0.f,0.f,0.f};
  f32x4 acc[2][4] = {{zero,zero,zero,zero},{zero,zero,zero,zero}};

  for (int kk = 0; kk < 512; kk += 32) {
    bf16x8 a0 = *(const bf16x8*)(A + (size_t)r0*512 + kk + lh*8);
    bf16x8 a1 = *(const bf16x8*)(A + (size_t)r1*512 + kk + lh*8);
#pragma unroll
    for (int t = 0; t < 4; ++t) {
      bf16x8 wf = *(const bf16x8*)(W + (size_t)(n0 + t*16 + lr)*512 + kk + lh*8);
      acc[0][t] = MFMA16(a0, wf, acc[0][t]);
      acc[1][t] = MFMA16(a1, wf, acc[1][t]);
    }
  }
#pragma unroll
  for (int g = 0; g < 2; ++g)
#pragma unroll
    for (int t = 0; t < 4; ++t) {
      const int ncol = n0 + t*16 + lr;
      const float bs = bias[ncol];
#pragma unroll
      for (int j = 0; j < 4; ++j) {
        const int m = m0 + w*32 + g*16 + lh*4 + j;
        out[(size_t)m*512 + ncol] = acc[g][t][j] + bs;
      }
    }
}

// ---------------------------------------------------------------------------
extern "C" void kernel_launch(void* const* d_in, const int* in_sizes, int n_in,
                              void* d_out, int out_size, void* d_ws, size_t ws_size,
                              hipStream_t stream) {
  const float* q    = (const float*)d_in[0];
  const float* k    = (const float*)d_in[1];
  const float* v    = (const float*)d_in[2];
  const int*   mask = (const int*)  d_in[3];
  const float* Wq   = (const float*)d_in[4];
  const float* Wk   = (const float*)d_in[5];
  const float* Wv   = (const float*)d_in[6];
  const float* fcw  = (const float*)d_in[7];
  const float* fcb  = (const float*)d_in[8];
  const float* g0   = (const float*)d_in[9];
  const float* b0   = (const float*)d_in[10];
  const float* g1   = (const float*)d_in[11];
  const float* b1   = (const float*)d_in[12];

  char* ws = (char*)d_ws;
  // weights bf16: [0,2MB)
  bf16*  Wqb  = (bf16*) (ws);
  bf16*  Wkb  = (bf16*) (ws + (512ull  << 10));
  bf16*  Wvb  = (bf16*) (ws + (1024ull << 10));
  bf16*  fcwb = (bf16*) (ws + (1536ull << 10));
  // live [proj, attn]:
  bf16*  qh   = (bf16*) (ws + (2ull  << 20));   //  8 MB [2,10)
  bf16*  kh   = (bf16*) (ws + (10ull << 20));   //  8 MB [10,18)
  bf16*  vhT  = (bf16*) (ws + (18ull << 20));   //  8 MB [18,26)
  float* attnb= (float*)(ws + (26ull << 20));   // 16 MB [26,42)
  // aliased after attn (qh/kh/vhT dead):
  float* x1   = (float*)(ws + (2ull  << 20));   // 16 MB over qh+kh
  bf16*  x1b  = (bf16*) (ws + (18ull << 20));   //  8 MB over vhT
  float* out  = (float*)d_out;

  cvt_kernel <<<dim3(256, 4),   256, 0, stream>>>(Wq, Wk, Wv, fcw, Wqb, Wkb, Wvb, fcwb);
  proj_kernel<<<dim3(64, 8, 3), 256, 0, stream>>>(q, k, v, Wqb, Wkb, Wvb, qh, kh, vhT);
  attn_kernel<<<dim3(16, 32),   256, 0, stream>>>(qh, kh, vhT, mask, attnb);
  ln_kernel  <<<2048,           256, 0, stream>>>(attnb, q, g0, b0, x1, x1b);
  fc_kernel  <<<dim3(64, 8),    256, 0, stream>>>(x1b, fcwb, fcb, out);
  ln_kernel  <<<2048,           256, 0, stream>>>(out, x1, g1, b1, out, nullptr);
}

// Round 7
// 156.621 us; speedup vs baseline: 3.8641x; 1.4583x over previous
//
#include <hip/hip_runtime.h>
#include <hip/hip_bf16.h>

typedef __bf16 bf16;
typedef bf16 bf16x8 __attribute__((ext_vector_type(8)));
typedef bf16 bf16x4 __attribute__((ext_vector_type(4)));
typedef float f32x4 __attribute__((ext_vector_type(4)));

#define MFMA16(a,b,c) __builtin_amdgcn_mfma_f32_16x16x32_bf16(a,b,c,0,0,0)

// async global->LDS, 16B per lane; LDS dest = wave-uniform base + lane*16
__device__ inline void gload_lds16(const bf16* g, bf16* l) {
  __builtin_amdgcn_global_load_lds(
      (const __attribute__((address_space(1))) unsigned int*)g,
      (__attribute__((address_space(3))) unsigned int*)l,
      16, 0, 0);
}

// swizzled fragment read: glob[r][cb*8..+8] lives at lds r*64 + (cb^(r&7))*8
__device__ inline bf16x8 ldsfrag(const bf16* base, int r, int cb) {
  return *(const bf16x8*)(base + r*64 + ((cb ^ (r & 7)) << 3));
}

// ---------------------------------------------------------------------------
// Bulk fp32 -> bf16 conversion. y selects the array.
//   y=0..2: q,k,v (4194304 elems)   y=3..6: Wq,Wk,Wv,fcw (262144 elems)
// ---------------------------------------------------------------------------
__global__ __launch_bounds__(256) void cvt_kernel(
    const float* __restrict__ q, const float* __restrict__ k_, const float* __restrict__ v,
    const float* __restrict__ Wq, const float* __restrict__ Wk, const float* __restrict__ Wv,
    const float* __restrict__ fcw,
    bf16* __restrict__ qb, bf16* __restrict__ kb, bf16* __restrict__ vb,
    bf16* __restrict__ Wqb, bf16* __restrict__ Wkb, bf16* __restrict__ Wvb,
    bf16* __restrict__ fcwb)
{
  const int y = blockIdx.y;
  const float* src; bf16* dst; int n;
  if      (y==0) { src=q;   dst=qb;   n=4194304; }
  else if (y==1) { src=k_;  dst=kb;   n=4194304; }
  else if (y==2) { src=v;   dst=vb;   n=4194304; }
  else if (y==3) { src=Wq;  dst=Wqb;  n=262144;  }
  else if (y==4) { src=Wk;  dst=Wkb;  n=262144;  }
  else if (y==5) { src=Wv;  dst=Wvb;  n=262144;  }
  else           { src=fcw; dst=fcwb; n=262144;  }
  const int i = (blockIdx.x*256 + threadIdx.x)*4;
  if (i >= n) return;
  f32x4 x = *(const f32x4*)(src + i);
  bf16x4 o;
  o[0]=(bf16)x[0]; o[1]=(bf16)x[1]; o[2]=(bf16)x[2]; o[3]=(bf16)x[3];
  *(bf16x4*)(dst + i) = o;
}

// ---------------------------------------------------------------------------
// QKV projection v7: LDS double-buffered GEMM (attn-v5 staging pattern).
// BM=128 BN=64 BK=64, 4 waves, 48KB LDS, one __syncthreads per K-step.
// qh gets the softmax scale (0.125*log2e) folded in. vhT stored transposed.
// ---------------------------------------------------------------------------
__global__ __launch_bounds__(256) void proj_kernel(
    const bf16* __restrict__ qb, const bf16* __restrict__ kb, const bf16* __restrict__ vb,
    const bf16* __restrict__ Wqb, const bf16* __restrict__ Wkb, const bf16* __restrict__ Wvb,
    bf16* __restrict__ qh, bf16* __restrict__ kh, bf16* __restrict__ vhT)
{
  const int p = blockIdx.z;
  const bf16* A = (p==0)?qb:(p==1)?kb:vb;
  const bf16* W = (p==0)?Wqb:(p==1)?Wkb:Wvb;
  const int m0 = blockIdx.x*128, n0 = blockIdx.y*64;
  const int l  = threadIdx.x & 63, w = threadIdx.x >> 6;
  const int lr = l & 15, lh = l >> 4;

  __shared__ bf16 sA[2][8192];   // [128][64] bf16, XOR-swizzled
  __shared__ bf16 sW[2][4096];   // [64][64]  bf16, XOR-swizzled

  auto stageA = [&](bf16* d, int kk) {
#pragma unroll
    for (int c = 0; c < 4; ++c) {
      const int i   = (w*4 + c)*64 + l;       // 16B-chunk in [0,1024)
      const int r   = i >> 3;
      const int cbs = (i & 7) ^ (r & 7);
      gload_lds16(A + (size_t)(m0 + r)*512 + kk + cbs*8, d + (w*4+c)*512);
    }
  };
  auto stageW = [&](bf16* d, int kk) {
#pragma unroll
    for (int c = 0; c < 2; ++c) {
      const int i   = (w*2 + c)*64 + l;       // 16B-chunk in [0,512)
      const int r   = i >> 3;
      const int cbs = (i & 7) ^ (r & 7);
      gload_lds16(W + (size_t)(n0 + r)*512 + kk + cbs*8, d + (w*2+c)*512);
    }
  };

  stageA(sA[0], 0); stageW(sW[0], 0);
  __syncthreads();

  f32x4 zero = {0.f,0.f,0.f,0.f};
  f32x4 acc[2][4] = {{zero,zero,zero,zero},{zero,zero,zero,zero}};

  int cur = 0;
#pragma unroll 1
  for (int kk = 0; kk < 512; kk += 64) {
    if (kk + 64 < 512) { stageA(sA[cur^1], kk+64); stageW(sW[cur^1], kk+64); }
    const bf16* a_ = sA[cur];
    const bf16* w_ = sW[cur];
#pragma unroll
    for (int s = 0; s < 2; ++s) {
      bf16x8 a0 = ldsfrag(a_, w*32 + lr,      s*4 + lh);
      bf16x8 a1 = ldsfrag(a_, w*32 + 16 + lr, s*4 + lh);
#pragma unroll
      for (int t = 0; t < 4; ++t) {
        bf16x8 wf = ldsfrag(w_, t*16 + lr, s*4 + lh);
        acc[0][t] = MFMA16(a0, wf, acc[0][t]);
        acc[1][t] = MFMA16(a1, wf, acc[1][t]);
      }
    }
    __syncthreads();
    cur ^= 1;
  }

  const float qscale = 0.18033688011112042f;  // 0.125 * log2(e)
#pragma unroll
  for (int g = 0; g < 2; ++g)
#pragma unroll
    for (int t = 0; t < 4; ++t) {
      const int ncol = n0 + t*16 + lr;
      const int h = ncol >> 6, d = ncol & 63;
#pragma unroll
      for (int j = 0; j < 4; ++j) {
        const int m   = m0 + w*32 + g*16 + lh*4 + j;
        const int b   = m >> 11, tok = m & 2047;
        float val = acc[g][t][j];
        if (p == 0) val *= qscale;
        const bf16 bv = (bf16)val;
        if (p == 0)      qh [((size_t)((h<<2)|b)*2048 + tok)*64 + d]   = bv;
        else if (p == 1) kh [((size_t)((h<<2)|b)*2048 + tok)*64 + d]   = bv;
        else             vhT[((size_t)((h<<2)|b)*64   + d)*2048 + tok] = bv;
      }
    }
}

// ---------------------------------------------------------------------------
// Attention v6 (unchanged from round 6): 32 queries/wave, LDS double-buffered
// K/V via global_load_lds + XOR swizzle, K/V frags register-reused across both
// 16-q groups, sP two-pass. Unnormalized exp2-clamped softmax, deferred sum.
// ---------------------------------------------------------------------------
__global__ __launch_bounds__(256, 3) void attn_kernel(
    const bf16* __restrict__ qh, const bf16* __restrict__ kh, const bf16* __restrict__ vhT,
    const int* __restrict__ mask, float* __restrict__ attn_out)
{
  const int n  = blockIdx.y;
  const int w  = threadIdx.x >> 6;
  const int l  = threadIdx.x & 63;
  const int lr = l & 15, lh = l >> 4;
  const int q0 = blockIdx.x*128 + w*32;
  const bf16* qn = qh  + (size_t)n*2048*64;
  const bf16* kn = kh  + (size_t)n*2048*64;
  const bf16* vn = vhT + (size_t)n*64*2048;
  const int h = n >> 2, b = n & 3;

  __shared__ float smask[2048];
  __shared__ bf16  sK[2][4096];
  __shared__ bf16  sV[2][4096];
  __shared__ bf16  sP[4][16][72];

  auto stage = [&](bf16* dK, bf16* dV, int kt_) {
#pragma unroll
    for (int c = 0; c < 2; ++c) {
      const int i   = (w*2 + c)*64 + l;
      const int r   = i >> 3;
      const int cbs = (i & 7) ^ (r & 7);
      gload_lds16(kn + (size_t)(kt_ + r)*64   + cbs*8, dK + (w*2+c)*512);
      gload_lds16(vn + (size_t)r*2048 + kt_   + cbs*8, dV + (w*2+c)*512);
    }
  };

  {
    const int* mn = mask + n*2048;
    const int i0 = (int)threadIdx.x * 8;
    int4 m0v = *(const int4*)(mn + i0);
    int4 m1v = *(const int4*)(mn + i0 + 4);
    f32x4 f0, f1;
    f0[0]=m0v.x?1.f:0.f; f0[1]=m0v.y?1.f:0.f; f0[2]=m0v.z?1.f:0.f; f0[3]=m0v.w?1.f:0.f;
    f1[0]=m1v.x?1.f:0.f; f1[1]=m1v.y?1.f:0.f; f1[2]=m1v.z?1.f:0.f; f1[3]=m1v.w?1.f:0.f;
    *(f32x4*)(smask + i0)     = f0;
    *(f32x4*)(smask + i0 + 4) = f1;
  }
  stage(sK[0], sV[0], 0);
  __syncthreads();

  bf16x8 aq[2][2];
#pragma unroll
  for (int g = 0; g < 2; ++g) {
    aq[g][0] = *(const bf16x8*)(qn + (size_t)(q0+g*16+lr)*64 + lh*8);
    aq[g][1] = *(const bf16x8*)(qn + (size_t)(q0+g*16+lr)*64 + 32 + lh*8);
  }

  f32x4 zero = {0.f,0.f,0.f,0.f};
  f32x4 acc[2][4] = {{zero,zero,zero,zero},{zero,zero,zero,zero}};
  float ssum[2][4] = {{0.f,0.f,0.f,0.f},{0.f,0.f,0.f,0.f}};

  int cur = 0;
#pragma unroll 1
  for (int kt = 0; kt < 2048; kt += 64) {
    const int ktn = kt + 64;
    if (ktn < 2048) stage(sK[cur^1], sV[cur^1], ktn);

    const bf16* sKc = sK[cur];
    const bf16* sVc = sV[cur];

    f32x4 sc[2][4] = {{zero,zero,zero,zero},{zero,zero,zero,zero}};
#pragma unroll
    for (int t = 0; t < 4; ++t) {
      bf16x8 bk0 = ldsfrag(sKc, t*16 + lr, lh);
      bf16x8 bk1 = ldsfrag(sKc, t*16 + lr, lh + 4);
      sc[0][t] = MFMA16(aq[0][0], bk0, sc[0][t]);
      sc[0][t] = MFMA16(aq[0][1], bk1, sc[0][t]);
      sc[1][t] = MFMA16(aq[1][0], bk0, sc[1][t]);
      sc[1][t] = MFMA16(aq[1][1], bk1, sc[1][t]);
    }
#pragma unroll
    for (int t = 0; t < 4; ++t) {
      const float msk = smask[kt + t*16 + lr];
#pragma unroll
      for (int g = 0; g < 2; ++g)
#pragma unroll
        for (int j = 0; j < 4; ++j) {
          const float e = exp2f(fminf(sc[g][t][j], 100.f)) * msk;
          sc[g][t][j] = e;
          ssum[g][j] += e;
        }
    }
    bf16x8 vf0[4], vf1[4];
#pragma unroll
    for (int dt = 0; dt < 4; ++dt) {
      vf0[dt] = ldsfrag(sVc, dt*16 + lr, lh);
      vf1[dt] = ldsfrag(sVc, dt*16 + lr, lh + 4);
    }
#pragma unroll
    for (int g = 0; g < 2; ++g) {
#pragma unroll
      for (int t = 0; t < 4; ++t)
#pragma unroll
        for (int j = 0; j < 4; ++j)
          sP[w][lh*4 + j][t*16 + lr] = (bf16)sc[g][t][j];
      asm volatile("s_waitcnt lgkmcnt(0)" ::: "memory");
      __builtin_amdgcn_sched_barrier(0);   // rule #18
      bf16x8 pa0 = *(const bf16x8*)(&sP[w][lr][lh*8]);
      bf16x8 pa1 = *(const bf16x8*)(&sP[w][lr][32 + lh*8]);
#pragma unroll
      for (int dt = 0; dt < 4; ++dt) {
        acc[g][dt] = MFMA16(pa0, vf0[dt], acc[g][dt]);
        acc[g][dt] = MFMA16(pa1, vf1[dt], acc[g][dt]);
      }
    }
    __syncthreads();
    cur ^= 1;
  }

#pragma unroll
  for (int off = 1; off < 16; off <<= 1)
#pragma unroll
    for (int g = 0; g < 2; ++g)
#pragma unroll
      for (int j = 0; j < 4; ++j)
        ssum[g][j] += __shfl_xor(ssum[g][j], off, 16);
#pragma unroll
  for (int g = 0; g < 2; ++g) {
    float inv[4];
#pragma unroll
    for (int j = 0; j < 4; ++j) inv[j] = (ssum[g][j] > 0.f) ? 1.f/ssum[g][j] : 0.f;
#pragma unroll
    for (int dt = 0; dt < 4; ++dt)
#pragma unroll
      for (int j = 0; j < 4; ++j) {
        const int tok = q0 + g*16 + lh*4 + j;
        const int dv  = dt*16 + lr;
        attn_out[((size_t)(b*2048 + tok))*512 + h*64 + dv] = acc[g][dt][j]*inv[j];
      }
  }
}

// ---------------------------------------------------------------------------
// LayerNorm of (xa + xb), wave per row. outb (bf16 copy) optional.
// NOTE: no __restrict__ on xa/outf — ln2 runs in-place on d_out.
// ---------------------------------------------------------------------------
__global__ __launch_bounds__(256) void ln_kernel(
    const float* xa, const float* xb,
    const float* __restrict__ g, const float* __restrict__ bb,
    float* outf, bf16* outb)
{
  const int row = blockIdx.x*4 + (threadIdx.x >> 6);
  const int l   = threadIdx.x & 63;
  const float* pa = xa + (size_t)row*512;
  const float* pb = xb + (size_t)row*512;
  f32x4 u0 = *(const f32x4*)(pa + 4*l);
  f32x4 u1 = *(const f32x4*)(pa + 256 + 4*l);
  f32x4 w0 = *(const f32x4*)(pb + 4*l);
  f32x4 w1 = *(const f32x4*)(pb + 256 + 4*l);
  u0 = u0 + w0; u1 = u1 + w1;
  float s = 0.f, sq = 0.f;
#pragma unroll
  for (int e = 0; e < 4; ++e) { s += u0[e] + u1[e]; sq += u0[e]*u0[e] + u1[e]*u1[e]; }
#pragma unroll
  for (int off = 1; off < 64; off <<= 1) {
    s  += __shfl_xor(s,  off, 64);
    sq += __shfl_xor(sq, off, 64);
  }
  const float mean = s * (1.f/512.f);
  const float var  = fmaxf(sq * (1.f/512.f) - mean*mean, 0.f);
  const float r    = rsqrtf(var + 1e-5f);
  f32x4 g0v = *(const f32x4*)(g + 4*l),  g1v = *(const f32x4*)(g + 256 + 4*l);
  f32x4 b0v = *(const f32x4*)(bb + 4*l), b1v = *(const f32x4*)(bb + 256 + 4*l);
  f32x4 o0, o1;
#pragma unroll
  for (int e = 0; e < 4; ++e) {
    o0[e] = (u0[e] - mean)*r*g0v[e] + b0v[e];
    o1[e] = (u1[e] - mean)*r*g1v[e] + b1v[e];
  }
  *(f32x4*)(outf + (size_t)row*512 + 4*l)       = o0;
  *(f32x4*)(outf + (size_t)row*512 + 256 + 4*l) = o1;
  if (outb) {
    bf16x4 ob0, ob1;
#pragma unroll
    for (int e = 0; e < 4; ++e) { ob0[e]=(bf16)o0[e]; ob1[e]=(bf16)o1[e]; }
    *(bf16x4*)(outb + (size_t)row*512 + 4*l)       = ob0;
    *(bf16x4*)(outb + (size_t)row*512 + 256 + 4*l) = ob1;
  }
}

// ---------------------------------------------------------------------------
// FC v7: same LDS double-buffered GEMM structure as proj. + bias, fp32 out.
// ---------------------------------------------------------------------------
__global__ __launch_bounds__(256) void fc_kernel(
    const bf16* __restrict__ A, const bf16* __restrict__ W,
    const float* __restrict__ bias, float* __restrict__ out)
{
  const int m0 = blockIdx.x*128, n0 = blockIdx.y*64;
  const int l  = threadIdx.x & 63, w = threadIdx.x >> 6;
  const int lr = l & 15, lh = l >> 4;

  __shared__ bf16 sA[2][8192];
  __shared__ bf16 sW[2][4096];

  auto stageA = [&](bf16* d, int kk) {
#pragma unroll
    for (int c = 0; c < 4; ++c) {
      const int i   = (w*4 + c)*64 + l;
      const int r   = i >> 3;
      const int cbs = (i & 7) ^ (r & 7);
      gload_lds16(A + (size_t)(m0 + r)*512 + kk + cbs*8, d + (w*4+c)*512);
    }
  };
  auto stageW = [&](bf16* d, int kk) {
#pragma unroll
    for (int c = 0; c < 2; ++c) {
      const int i   = (w*2 + c)*64 + l;
      const int r   = i >> 3;
      const int cbs = (i & 7) ^ (r & 7);
      gload_lds16(W + (size_t)(n0 + r)*512 + kk + cbs*8, d + (w*2+c)*512);
    }
  };

  stageA(sA[0], 0); stageW(sW[0], 0);
  __syncthreads();

  f32x4 zero = {0.f,0.f,0.f,0.f};
  f32x4 acc[2][4] = {{zero,zero,zero,zero},{zero,zero,zero,zero}};

  int cur = 0;
#pragma unroll 1
  for (int kk = 0; kk < 512; kk += 64) {
    if (kk + 64 < 512) { stageA(sA[cur^1], kk+64); stageW(sW[cur^1], kk+64); }
    const bf16* a_ = sA[cur];
    const bf16* w_ = sW[cur];
#pragma unroll
    for (int s = 0; s < 2; ++s) {
      bf16x8 a0 = ldsfrag(a_, w*32 + lr,      s*4 + lh);
      bf16x8 a1 = ldsfrag(a_, w*32 + 16 + lr, s*4 + lh);
#pragma unroll
      for (int t = 0; t < 4; ++t) {
        bf16x8 wf = ldsfrag(w_, t*16 + lr, s*4 + lh);
        acc[0][t] = MFMA16(a0, wf, acc[0][t]);
        acc[1][t] = MFMA16(a1, wf, acc[1][t]);
      }
    }
    __syncthreads();
    cur ^= 1;
  }

#pragma unroll
  for (int g = 0; g < 2; ++g)
#pragma unroll
    for (int t = 0; t < 4; ++t) {
      const int ncol = n0 + t*16 + lr;
      const float bs = bias[ncol];
#pragma unroll
      for (int j = 0; j < 4; ++j) {
        const int m = m0 + w*32 + g*16 + lh*4 + j;
        out[(size_t)m*512 + ncol] = acc[g][t][j] + bs;
      }
    }
}

// ---------------------------------------------------------------------------
extern "C" void kernel_launch(void* const* d_in, const int* in_sizes, int n_in,
                              void* d_out, int out_size, void* d_ws, size_t ws_size,
                              hipStream_t stream) {
  const float* q    = (const float*)d_in[0];
  const float* k    = (const float*)d_in[1];
  const float* v    = (const float*)d_in[2];
  const int*   mask = (const int*)  d_in[3];
  const float* Wq   = (const float*)d_in[4];
  const float* Wk   = (const float*)d_in[5];
  const float* Wv   = (const float*)d_in[6];
  const float* fcw  = (const float*)d_in[7];
  const float* fcb  = (const float*)d_in[8];
  const float* g0   = (const float*)d_in[9];
  const float* b0   = (const float*)d_in[10];
  const float* g1   = (const float*)d_in[11];
  const float* b1   = (const float*)d_in[12];

  char* ws = (char*)d_ws;
  // live [cvt, proj/fc]:
  bf16*  qb   = (bf16*) (ws);                                  //  8 MB [0,8)
  bf16*  kb   = (bf16*) (ws + (8ull  << 20));                  //  8 MB [8,16)
  bf16*  vb   = (bf16*) (ws + (16ull << 20));                  //  8 MB [16,24)
  bf16*  Wqb  = (bf16*) (ws + (24ull << 20));                  // [24,24.5)
  bf16*  Wkb  = (bf16*) (ws + (24ull << 20) + (512ull << 10)); // [24.5,25)
  bf16*  Wvb  = (bf16*) (ws + (25ull << 20));                  // [25,25.5)
  bf16*  fcwb = (bf16*) (ws + (25ull << 20) + (512ull << 10)); // [25.5,26)
  // live [proj, attn]:
  bf16*  qh   = (bf16*) (ws + (26ull << 20));                  //  8 MB [26,34)
  bf16*  kh   = (bf16*) (ws + (34ull << 20));                  //  8 MB [34,42)
  bf16*  vhT  = (bf16*) (ws + (42ull << 20));                  //  8 MB [42,50)
  // aliased (lifetimes disjoint):
  float* attnb= (float*)(ws);                                  // 16 MB over qb+kb (dead)
  float* x1   = (float*)(ws + (26ull << 20));                  // 16 MB over qh+kh (dead)
  bf16*  x1b  = (bf16*) (ws + (50ull << 20));                  //  8 MB [50,58) fresh
  float* out  = (float*)d_out;

  cvt_kernel <<<dim3(4096, 7), 256, 0, stream>>>(q, k, v, Wq, Wk, Wv, fcw,
                                                 qb, kb, vb, Wqb, Wkb, Wvb, fcwb);
  proj_kernel<<<dim3(64, 8, 3), 256, 0, stream>>>(qb, kb, vb, Wqb, Wkb, Wvb, qh, kh, vhT);
  attn_kernel<<<dim3(16, 32),   256, 0, stream>>>(qh, kh, vhT, mask, attnb);
  ln_kernel  <<<2048,           256, 0, stream>>>(attnb, q, g0, b0, x1, x1b);
  fc_kernel  <<<dim3(64, 8),    256, 0, stream>>>(x1b, fcwb, fcb, out);
  ln_kernel  <<<2048,           256, 0, stream>>>(out, x1, g1, b1, out, nullptr);
}